// Round 2
// baseline (118378.943 us; speedup 1.0000x reference)
//
#include <hip/hip_runtime.h>
#include <math.h>

#define NBLK 256
#define TPB  512
#define RLD  17          // padded row stride (floats) in reduction tile

// ---------------- static device state (rewritten every call) ----------------
__device__ int g_bar[2];            // {count, generation} — self-restoring barrier
__device__ int g_tok[64];
__device__ int g_done[64];
__device__ __attribute__((aligned(16))) float g_hA[64 * 3584];
__device__ __attribute__((aligned(16))) float g_hB[64 * 3584];
__device__ __attribute__((aligned(16))) float g_v0h[64 * 1024];
__device__ __attribute__((aligned(16))) float g_v1[64 * 2048];
__device__ __attribute__((aligned(16))) float g_c1x[64 * 1024];
__device__ __attribute__((aligned(16))) float g_v2[64 * 4096];
__device__ __attribute__((aligned(16))) float g_c2x[64 * 2048];
__device__ __attribute__((aligned(16))) float g_ekg[40 * 1024];
__device__ __attribute__((aligned(16))) float g_ekc[40 * 512];

__device__ __forceinline__ float sigf(float x) { return 1.0f / (1.0f + __expf(-x)); }
__device__ __forceinline__ float tanhf_(float x) {
  float ax = fabsf(x);
  float e  = __expf(-2.0f * ax);
  float r  = (1.0f - e) / (1.0f + e);
  return copysignf(r, x);
}

// grid-wide barrier: sense via generation counter, device-scope atomics.
// Co-residency of all NBLK blocks is guaranteed by hipLaunchCooperativeKernel.
__device__ __forceinline__ void gbar() {
  __syncthreads();
  __threadfence();
  if (threadIdx.x == 0) {
    int g = __hip_atomic_load(&g_bar[1], __ATOMIC_RELAXED, __HIP_MEMORY_SCOPE_AGENT);
    int a = __hip_atomic_fetch_add(&g_bar[0], 1, __ATOMIC_ACQ_REL, __HIP_MEMORY_SCOPE_AGENT);
    if (a == NBLK - 1) {
      __hip_atomic_store(&g_bar[0], 0, __ATOMIC_RELAXED, __HIP_MEMORY_SCOPE_AGENT);
      __hip_atomic_store(&g_bar[1], g + 1, __ATOMIC_RELEASE, __HIP_MEMORY_SCOPE_AGENT);
    } else {
      while (__hip_atomic_load(&g_bar[1], __ATOMIC_ACQUIRE, __HIP_MEMORY_SCOPE_AGENT) == g) {
        __builtin_amdgcn_s_sleep(2);
      }
    }
  }
  __syncthreads();
  __threadfence();
}

// ---------------- A-matrix accessors ----------------
struct AccP {   // plain [r][k], row stride lda
  const float* p; int lda;
  __device__ __forceinline__ float4 ld(int r, int k) const {
    return *(const float4*)(p + (size_t)r * lda + k);
  }
};
struct AccH {   // hcat row, k<cut from pn, else po; both at hcat offset `off`
  const float* pn; const float* po; int off; int cut;
  __device__ __forceinline__ float4 ld(int r, int k) const {
    const float* b = (k < cut) ? pn : po;
    return *(const float4*)(b + (size_t)r * 3584 + off + k);
  }
};
struct AccRH0 { // layer0 candidate A: sigmoid(v0h + ekg[tok]) * h0_old
  const float* v; const float* ek; const int* tk; const float* h;
  __device__ __forceinline__ float4 ld(int r, int k) const {
    int t = tk[r];
    float4 a  = *(const float4*)(v + (size_t)r * 1024 + k);
    float4 b  = *(const float4*)(ek + (size_t)t * 1024 + k);
    float4 hh = *(const float4*)(h + (size_t)r * 3584 + k);
    return make_float4(sigf(a.x + b.x) * hh.x, sigf(a.y + b.y) * hh.y,
                       sigf(a.z + b.z) * hh.z, sigf(a.w + b.w) * hh.w);
  }
};
struct AccRH {  // layer1/2 candidate A: sigmoid(v) * h_old
  const float* v; int ldv; const float* h;   // h already offset into hcat
  __device__ __forceinline__ float4 ld(int r, int k) const {
    float4 a  = *(const float4*)(v + (size_t)r * ldv + k);
    float4 hh = *(const float4*)(h + (size_t)r * 3584 + k);
    return make_float4(sigf(a.x) * hh.x, sigf(a.y) * hh.y,
                       sigf(a.z) * hh.z, sigf(a.w) * hh.w);
  }
};

// ---------------- split-K GEMM chunk: M=64 x 16 cols ----------------
// 16 k-slices (one per half-wave); half-wave pairs merged in-register via
// __shfl_xor(.,32), so only 8 slices hit LDS. red = 8*64*RLD floats (~34.8KB).
// thread: s = tid>>5 (k-slice), rg = tid&7 (8 rows), cg = (tid>>3)&3 (4 cols)
template <class AF, class EF>
__device__ __forceinline__ void gemm_chunk(const AF& A, const float* __restrict__ W,
                                           const int ldw, const int c0, const int K,
                                           float* __restrict__ red, const EF& epi) {
  const int tid = threadIdx.x;
  const int s  = tid >> 5;
  const int rg = tid & 7;
  const int cg = (tid >> 3) & 3;
  const int Ks = K >> 4;              // K multiple of 64 -> Ks multiple of 4
  const int kb = Ks * s;
  const int cc = c0 + cg * 4;
  const int r0 = rg * 8;
  float acc[8][4];
#pragma unroll
  for (int r = 0; r < 8; ++r)
#pragma unroll
    for (int c = 0; c < 4; ++c) acc[r][c] = 0.0f;

  for (int k = 0; k < Ks; k += 4) {
    const int kk = kb + k;
    const float* wp = W + (size_t)kk * ldw + cc;
    const float4 w0 = *(const float4*)(wp);
    const float4 w1 = *(const float4*)(wp + ldw);
    const float4 w2 = *(const float4*)(wp + 2 * (size_t)ldw);
    const float4 w3 = *(const float4*)(wp + 3 * (size_t)ldw);
#pragma unroll
    for (int r = 0; r < 8; ++r) {
      const float4 a = A.ld(r0 + r, kk);
      acc[r][0] = fmaf(a.w, w3.x, fmaf(a.z, w2.x, fmaf(a.y, w1.x, fmaf(a.x, w0.x, acc[r][0]))));
      acc[r][1] = fmaf(a.w, w3.y, fmaf(a.z, w2.y, fmaf(a.y, w1.y, fmaf(a.x, w0.y, acc[r][1]))));
      acc[r][2] = fmaf(a.w, w3.z, fmaf(a.z, w2.z, fmaf(a.y, w1.z, fmaf(a.x, w0.z, acc[r][2]))));
      acc[r][3] = fmaf(a.w, w3.w, fmaf(a.z, w2.w, fmaf(a.y, w1.w, fmaf(a.x, w0.w, acc[r][3]))));
    }
  }
  // merge the two half-wave k-slices of each wave in-register
#pragma unroll
  for (int r = 0; r < 8; ++r)
#pragma unroll
    for (int c = 0; c < 4; ++c) acc[r][c] += __shfl_xor(acc[r][c], 32);

  __syncthreads();                     // red free from previous use
  if ((tid & 32) == 0) {
    const int w = tid >> 6;            // 8 wave-slices
#pragma unroll
    for (int r = 0; r < 8; ++r)
#pragma unroll
      for (int c = 0; c < 4; ++c)
        red[w * (64 * RLD) + (r0 + r) * RLD + cg * 4 + c] = acc[r][c];
  }
  __syncthreads();
#pragma unroll
  for (int i = 0; i < 2; ++i) {
    const int o = tid * 2 + i;
    const int row = o >> 4, col = o & 15;
    float v = 0.0f;
#pragma unroll
    for (int s2 = 0; s2 < 8; ++s2) v += red[s2 * (64 * RLD) + row * RLD + col];
    epi(row, c0 + col, v);
  }
}

// ---------------- the persistent kernel ----------------
__global__ void __launch_bounds__(TPB) decoder_kernel(
    const float* __restrict__ input_vecs, const float* __restrict__ emb,
    const float* __restrict__ dense_W, const float* __restrict__ dense_b,
    const float* __restrict__ dec_W,
    const float* __restrict__ Kg0, const float* __restrict__ bg0,
    const float* __restrict__ Kc0, const float* __restrict__ bc0,
    const float* __restrict__ Kg1, const float* __restrict__ bg1,
    const float* __restrict__ Kc1, const float* __restrict__ bc1,
    const float* __restrict__ Kg2, const float* __restrict__ bg2,
    const float* __restrict__ Kc2, const float* __restrict__ bc2,
    float* __restrict__ out) {
  __shared__ float red[8 * 64 * RLD];
  __shared__ float lg[40];
  const int bid = blockIdx.x;
  const int tid = threadIdx.x;

  // ---- init phase: h = input_vecs @ dense_W + dense_b; emb tables; tok/done ----
  for (int ch = bid; ch < 224; ch += NBLK) {
    AccP A{input_vecs, 512};
    auto epi = [&](int r, int c, float a) { g_hA[(size_t)r * 3584 + c] = a + dense_b[c]; };
    gemm_chunk(A, dense_W, 3584, ch * 16, 512, red, epi);
  }
  if (bid >= 224) {
    int base = (bid - 224) * 1920;
    for (int o = base + tid; o < base + 1920; o += TPB) {
      if (o < 40960) {
        int r = o >> 10, c = o & 1023;
        float s = 0.0f;
        for (int k = 0; k < 32; ++k) s += emb[r * 32 + k] * Kg0[k * 1024 + c];
        g_ekg[o] = s;
      } else {
        int o2 = o - 40960;
        int r = o2 >> 9, c = o2 & 511;
        float s = 0.0f;
        for (int k = 0; k < 32; ++k) s += emb[r * 32 + k] * Kc0[k * 512 + c];
        g_ekc[o2] = s;
      }
    }
  }
  if (bid == 255 && tid < 64) { g_tok[tid] = 39; g_done[tid] = 0; }
  gbar();

  // ---- gates0h for t=0: v0h = bg0 + h0 @ Kg0h ----
  for (int ch = bid; ch < 64; ch += NBLK) {
    AccH A{g_hA, g_hA, 0, 512};
    auto epi = [&](int r, int c, float a) { g_v0h[r * 1024 + c] = a + bg0[c]; };
    gemm_chunk(A, Kg0 + 32 * 1024, 1024, ch * 16, 512, red, epi);
  }
  gbar();

  for (int t = 0; t < 50; ++t) {
    const float* hOld = (t & 1) ? g_hB : g_hA;
    float*       hNew = (t & 1) ? g_hA : g_hB;

    // Ph2: cand0 -> h0'   (N=512, K=512)
    for (int ch = bid; ch < 32; ch += NBLK) {
      AccRH0 A{g_v0h, g_ekg, g_tok, hOld};
      auto epi = [&](int r, int c, float a) {
        int tk = g_tok[r];
        float cx = g_ekc[tk * 512 + c] + bc0[c];
        float z  = sigf(g_v0h[r * 1024 + 512 + c] + g_ekg[tk * 1024 + 512 + c]);
        float ho = hOld[(size_t)r * 3584 + c];
        hNew[(size_t)r * 3584 + c] = z * ho + (1.0f - z) * tanhf_(a + cx);
      };
      gemm_chunk(A, Kc0 + 32 * 512, 512, ch * 16, 512, red, epi);
    }
    gbar();

    // Ph3: gates1 (N=2048,K=1536) + c1x (N=1024,K=512)
    for (int ch = bid; ch < 192; ch += NBLK) {
      AccH A{hNew, hOld, 0, 512};
      if (ch < 128) {
        auto epi = [&](int r, int c, float a) { g_v1[r * 2048 + c] = a + bg1[c]; };
        gemm_chunk(A, Kg1, 2048, ch * 16, 1536, red, epi);
      } else {
        auto epi = [&](int r, int c, float a) { g_c1x[r * 1024 + c] = a + bc1[c]; };
        gemm_chunk(A, Kc1, 1024, (ch - 128) * 16, 512, red, epi);
      }
    }
    gbar();

    // Ph4: cand1 -> h1'  (N=1024, K=1024)
    for (int ch = bid; ch < 64; ch += NBLK) {
      AccRH A{g_v1, 2048, hOld + 512};
      auto epi = [&](int r, int c, float a) {
        float z  = sigf(g_v1[r * 2048 + 1024 + c]);
        float cx = g_c1x[r * 1024 + c];
        float ho = hOld[(size_t)r * 3584 + 512 + c];
        hNew[(size_t)r * 3584 + 512 + c] = z * ho + (1.0f - z) * tanhf_(a + cx);
      };
      gemm_chunk(A, Kc1 + 512 * 1024, 1024, ch * 16, 1024, red, epi);
    }
    gbar();

    // Ph5: gates2 (N=4096,K=3072) + c2x (N=2048,K=1024)
    for (int ch = bid; ch < 384; ch += NBLK) {
      AccH A{hNew, hOld, 512, 1024};
      if (ch < 256) {
        auto epi = [&](int r, int c, float a) { g_v2[r * 4096 + c] = a + bg2[c]; };
        gemm_chunk(A, Kg2, 4096, ch * 16, 3072, red, epi);
      } else {
        auto epi = [&](int r, int c, float a) { g_c2x[r * 2048 + c] = a + bc2[c]; };
        gemm_chunk(A, Kc2, 2048, (ch - 256) * 16, 1024, red, epi);
      }
    }
    gbar();

    // Ph6: cand2 -> h2'  (N=2048, K=2048)
    for (int ch = bid; ch < 128; ch += NBLK) {
      AccRH A{g_v2, 4096, hOld + 1536};
      auto epi = [&](int r, int c, float a) {
        float z  = sigf(g_v2[r * 4096 + 2048 + c]);
        float cx = g_c2x[r * 2048 + c];
        float ho = hOld[(size_t)r * 3584 + 1536 + c];
        hNew[(size_t)r * 3584 + 1536 + c] = z * ho + (1.0f - z) * tanhf_(a + cx);
      };
      gemm_chunk(A, Kc2 + 1024 * 2048, 2048, ch * 16, 2048, red, epi);
    }
    gbar();

    // Ph7: decode(t) on blocks 0..63  ||  gates0h(t+1) on blocks 64..127
    if (bid < 64) {
      const int b = bid;
      float acc = 0.0f;
      if (tid < 320) {
        const int v = tid >> 3, p = tid & 7;
        for (int i = 0; i < 64; ++i) {
          const int k = p * 4 + i * 32;
          float4 h = *(const float4*)(hNew + (size_t)b * 3584 + 1536 + k);
          acc += h.x * dec_W[k * 40 + v] + h.y * dec_W[(k + 1) * 40 + v] +
                 h.z * dec_W[(k + 2) * 40 + v] + h.w * dec_W[(k + 3) * 40 + v];
        }
        acc += __shfl_xor(acc, 4);
        acc += __shfl_xor(acc, 2);
        acc += __shfl_xor(acc, 1);
        if (p == 0) lg[v] = acc;
      }
      __syncthreads();
      if (tid == 0) {
        int idx = 0; float best = lg[0];
        for (int v = 1; v < 40; ++v) { if (lg[v] > best) { best = lg[v]; idx = v; } }
        const int dn = g_done[b];
        out[b * 50 + t] = dn ? 0.0f : (float)idx;
        float* olg = out + 3200 + (size_t)(b * 50 + t) * 40;
        for (int v = 0; v < 40; ++v) olg[v] = dn ? 0.0f : lg[v];
        if (!dn) { g_tok[b] = idx; if (idx == 0) g_done[b] = 1; }
      }
    } else {
      for (int ch = bid - 64; ch < 64; ch += 192) {
        AccH A{hNew, hOld, 0, 512};   // reads h0' (all-new)
        auto epi = [&](int r, int c, float a) { g_v0h[r * 1024 + c] = a + bg0[c]; };
        gemm_chunk(A, Kg0 + 32 * 1024, 1024, ch * 16, 512, red, epi);
      }
    }
    gbar();
  }
}

extern "C" void kernel_launch(void* const* d_in, const int* in_sizes, int n_in,
                              void* d_out, int out_size, void* d_ws, size_t ws_size,
                              hipStream_t stream) {
  (void)in_sizes; (void)n_in; (void)d_ws; (void)ws_size; (void)out_size;
  void* p0  = d_in[0];  void* p1  = d_in[1];  void* p2  = d_in[2];
  void* p3  = d_in[3];  void* p4  = d_in[4];  void* p5  = d_in[5];
  void* p6  = d_in[6];  void* p7  = d_in[7];  void* p8  = d_in[8];
  void* p9  = d_in[9];  void* p10 = d_in[10]; void* p11 = d_in[11];
  void* p12 = d_in[12]; void* p13 = d_in[13]; void* p14 = d_in[14];
  void* p15 = d_in[15]; void* p16 = d_in[16]; void* po  = d_out;
  void* args[] = {&p0, &p1, &p2, &p3, &p4, &p5, &p6, &p7, &p8,
                  &p9, &p10, &p11, &p12, &p13, &p14, &p15, &p16, &po};
  hipLaunchCooperativeKernel((const void*)decoder_kernel, dim3(NBLK), dim3(TPB),
                             args, 0, stream);
}

// Round 5
// 28812.204 us; speedup vs baseline: 4.1086x; 4.1086x over previous
//
#include <hip/hip_runtime.h>
#include <math.h>

#define NBLK 256
#define TPB  512
#define RLD  17          // padded row stride (floats) in reduction tile

// ---------------- static device state (rewritten every call) ----------------
// g_bar: [0]=monotonic arrive count, [32]=monotonic generation, [64]=abort flag
// (three separate 128B cache lines)
__device__ unsigned g_bar[96];
__device__ int g_tok[64];
__device__ int g_done[64];
__device__ __attribute__((aligned(16))) float g_hA[64 * 3584];
__device__ __attribute__((aligned(16))) float g_hB[64 * 3584];
__device__ __attribute__((aligned(16))) float g_v0h[64 * 1024];
__device__ __attribute__((aligned(16))) float g_v1[64 * 2048];
__device__ __attribute__((aligned(16))) float g_c1x[64 * 1024];
__device__ __attribute__((aligned(16))) float g_v2[64 * 4096];
__device__ __attribute__((aligned(16))) float g_c2x[64 * 2048];
__device__ __attribute__((aligned(16))) float g_ekg[40 * 1024];
__device__ __attribute__((aligned(16))) float g_ekc[40 * 512];

__device__ __forceinline__ float sigf(float x) { return 1.0f / (1.0f + __expf(-x)); }
__device__ __forceinline__ float tanhf_(float x) {
  float ax = fabsf(x);
  float e  = __expf(-2.0f * ax);
  float r  = (1.0f - e) / (1.0f + e);
  return copysignf(r, x);
}

// Coherent-point read-modify-write. Agent-scope RMWs MUST execute at the
// device-coherent point (cross-XCD safe) regardless of ordering — unlike
// relaxed loads/stores, which may be served stale from the XCD-local L2
// (the R4 deadlock). v=0 gives a guaranteed-fresh read.
__device__ __forceinline__ unsigned armw(unsigned* p, unsigned v) {
  return __hip_atomic_fetch_add(p, v, __ATOMIC_RELAXED, __HIP_MEMORY_SCOPE_AGENT);
}

// Grid barrier. Data visibility: ONE release fence (wbl2) before arrival, ONE
// acquire fence (buffer_inv per wave) after exit — R2-proven structure. All
// flag traffic is RMW (coherent by construction). Monotonic count/gen survive
// graph replays (wrap-safe unsigned). Deterministic poll-count timeout sets a
// global abort so a deadlock becomes a fast wrong answer, not a dead node.
__device__ __forceinline__ void gbar() {
  __syncthreads();                       // per-wave vmcnt(0): stores are in L2
  if (threadIdx.x == 0) {
    __builtin_amdgcn_fence(__ATOMIC_RELEASE, "agent");   // wbl2 once
    if (armw(&g_bar[64], 0u) == 0u) {
      unsigned g = armw(&g_bar[32], 0u);
      unsigned a = armw(&g_bar[0], 1u);
      if (a - g * (unsigned)NBLK == (unsigned)(NBLK - 1)) {
        armw(&g_bar[32], 1u);            // publish: coherent RMW
      } else {
        unsigned polls = 0u;
        while (armw(&g_bar[32], 0u) == g) {
          __builtin_amdgcn_s_sleep(32);
          if ((++polls & 63u) == 0u) {
            if (polls > (1u << 19)) { armw(&g_bar[64], 1u); break; }
            if (armw(&g_bar[64], 0u) != 0u) break;
          }
        }
      }
    }
  }
  __syncthreads();
  __builtin_amdgcn_fence(__ATOMIC_ACQUIRE, "agent");     // one buffer_inv per wave
}

// ---------------- A-matrix accessors ----------------
struct AccP {   // plain [r][k], row stride lda
  const float* p; int lda;
  __device__ __forceinline__ float4 ld(int r, int k) const {
    return *(const float4*)(p + (size_t)r * lda + k);
  }
};
struct AccH {   // hcat row, k<cut from pn, else po; both at hcat offset `off`
  const float* pn; const float* po; int off; int cut;
  __device__ __forceinline__ float4 ld(int r, int k) const {
    const float* b = (k < cut) ? pn : po;
    return *(const float4*)(b + (size_t)r * 3584 + off + k);
  }
};
struct AccRH0 { // layer0 candidate A: sigmoid(v0h + ekg[tok]) * h0_old
  const float* v; const float* ek; const int* tk; const float* h;
  __device__ __forceinline__ float4 ld(int r, int k) const {
    int t = tk[r];
    float4 a  = *(const float4*)(v + (size_t)r * 1024 + k);
    float4 b  = *(const float4*)(ek + (size_t)t * 1024 + k);
    float4 hh = *(const float4*)(h + (size_t)r * 3584 + k);
    return make_float4(sigf(a.x + b.x) * hh.x, sigf(a.y + b.y) * hh.y,
                       sigf(a.z + b.z) * hh.z, sigf(a.w + b.w) * hh.w);
  }
};
struct AccRH {  // layer1/2 candidate A: sigmoid(v) * h_old
  const float* v; int ldv; const float* h;   // h already offset into hcat
  __device__ __forceinline__ float4 ld(int r, int k) const {
    float4 a  = *(const float4*)(v + (size_t)r * ldv + k);
    float4 hh = *(const float4*)(h + (size_t)r * 3584 + k);
    return make_float4(sigf(a.x) * hh.x, sigf(a.y) * hh.y,
                       sigf(a.z) * hh.z, sigf(a.w) * hh.w);
  }
};

// ---------------- split-K GEMM chunk: M=64 x 16 cols ----------------
// 16 k-slices (one per half-wave); half-wave pairs merged in-register via
// __shfl_xor(.,32), so only 8 slices hit LDS. red = 8*64*RLD floats (~34.8KB).
// thread: s = tid>>5 (k-slice), rg = tid&7 (8 rows), cg = (tid>>3)&3 (4 cols)
template <class AF, class EF>
__device__ __forceinline__ void gemm_chunk(const AF& A, const float* __restrict__ W,
                                           const int ldw, const int c0, const int K,
                                           float* __restrict__ red, const EF& epi) {
  const int tid = threadIdx.x;
  const int s  = tid >> 5;
  const int rg = tid & 7;
  const int cg = (tid >> 3) & 3;
  const int Ks = K >> 4;              // K multiple of 64 -> Ks multiple of 4
  const int kb = Ks * s;
  const int cc = c0 + cg * 4;
  const int r0 = rg * 8;
  float acc[8][4];
#pragma unroll
  for (int r = 0; r < 8; ++r)
#pragma unroll
    for (int c = 0; c < 4; ++c) acc[r][c] = 0.0f;

  for (int k = 0; k < Ks; k += 4) {
    const int kk = kb + k;
    const float* wp = W + (size_t)kk * ldw + cc;
    const float4 w0 = *(const float4*)(wp);
    const float4 w1 = *(const float4*)(wp + ldw);
    const float4 w2 = *(const float4*)(wp + 2 * (size_t)ldw);
    const float4 w3 = *(const float4*)(wp + 3 * (size_t)ldw);
#pragma unroll
    for (int r = 0; r < 8; ++r) {
      const float4 a = A.ld(r0 + r, kk);
      acc[r][0] = fmaf(a.w, w3.x, fmaf(a.z, w2.x, fmaf(a.y, w1.x, fmaf(a.x, w0.x, acc[r][0]))));
      acc[r][1] = fmaf(a.w, w3.y, fmaf(a.z, w2.y, fmaf(a.y, w1.y, fmaf(a.x, w0.y, acc[r][1]))));
      acc[r][2] = fmaf(a.w, w3.z, fmaf(a.z, w2.z, fmaf(a.y, w1.z, fmaf(a.x, w0.z, acc[r][2]))));
      acc[r][3] = fmaf(a.w, w3.w, fmaf(a.z, w2.w, fmaf(a.y, w1.w, fmaf(a.x, w0.w, acc[r][3]))));
    }
  }
  // merge the two half-wave k-slices of each wave in-register
#pragma unroll
  for (int r = 0; r < 8; ++r)
#pragma unroll
    for (int c = 0; c < 4; ++c) acc[r][c] += __shfl_xor(acc[r][c], 32);

  __syncthreads();                     // red free from previous use
  if ((tid & 32) == 0) {
    const int w = tid >> 6;            // 8 wave-slices
#pragma unroll
    for (int r = 0; r < 8; ++r)
#pragma unroll
      for (int c = 0; c < 4; ++c)
        red[w * (64 * RLD) + (r0 + r) * RLD + cg * 4 + c] = acc[r][c];
  }
  __syncthreads();
#pragma unroll
  for (int i = 0; i < 2; ++i) {
    const int o = tid * 2 + i;
    const int row = o >> 4, col = o & 15;
    float v = 0.0f;
#pragma unroll
    for (int s2 = 0; s2 < 8; ++s2) v += red[s2 * (64 * RLD) + row * RLD + col];
    epi(row, c0 + col, v);
  }
}

// ---------------- the persistent kernel ----------------
__global__ void __launch_bounds__(TPB) decoder_kernel(
    const float* __restrict__ input_vecs, const float* __restrict__ emb,
    const float* __restrict__ dense_W, const float* __restrict__ dense_b,
    const float* __restrict__ dec_W,
    const float* __restrict__ Kg0, const float* __restrict__ bg0,
    const float* __restrict__ Kc0, const float* __restrict__ bc0,
    const float* __restrict__ Kg1, const float* __restrict__ bg1,
    const float* __restrict__ Kc1, const float* __restrict__ bc1,
    const float* __restrict__ Kg2, const float* __restrict__ bg2,
    const float* __restrict__ Kc2, const float* __restrict__ bc2,
    float* __restrict__ out) {
  __shared__ float red[8 * 64 * RLD];
  __shared__ float lg[40];
  const int bid = blockIdx.x;
  const int tid = threadIdx.x;

  // ---- init phase: h = input_vecs @ dense_W + dense_b; emb tables; tok/done ----
  for (int ch = bid; ch < 224; ch += NBLK) {
    AccP A{input_vecs, 512};
    auto epi = [&](int r, int c, float a) { g_hA[(size_t)r * 3584 + c] = a + dense_b[c]; };
    gemm_chunk(A, dense_W, 3584, ch * 16, 512, red, epi);
  }
  if (bid >= NBLK - 32) {
    int base = (bid - (NBLK - 32)) * 1920;
    for (int o = base + tid; o < base + 1920; o += TPB) {
      if (o < 40960) {
        int r = o >> 10, c = o & 1023;
        float s = 0.0f;
        for (int k = 0; k < 32; ++k) s += emb[r * 32 + k] * Kg0[k * 1024 + c];
        g_ekg[o] = s;
      } else {
        int o2 = o - 40960;
        int r = o2 >> 9, c = o2 & 511;
        float s = 0.0f;
        for (int k = 0; k < 32; ++k) s += emb[r * 32 + k] * Kc0[k * 512 + c];
        g_ekc[o2] = s;
      }
    }
  }
  if (bid == 0 && tid < 64) { g_tok[tid] = 39; g_done[tid] = 0; }
  gbar();

  // ---- gates0h for t=0: v0h = bg0 + h0 @ Kg0h ----
  for (int ch = bid; ch < 64; ch += NBLK) {
    AccH A{g_hA, g_hA, 0, 512};
    auto epi = [&](int r, int c, float a) { g_v0h[r * 1024 + c] = a + bg0[c]; };
    gemm_chunk(A, Kg0 + 32 * 1024, 1024, ch * 16, 512, red, epi);
  }
  gbar();

  for (int t = 0; t < 50; ++t) {
    const float* hOld = (t & 1) ? g_hB : g_hA;
    float*       hNew = (t & 1) ? g_hA : g_hB;

    // Ph2: cand0 -> h0'   (N=512, K=512)
    for (int ch = bid; ch < 32; ch += NBLK) {
      AccRH0 A{g_v0h, g_ekg, g_tok, hOld};
      auto epi = [&](int r, int c, float a) {
        int tk = g_tok[r];
        float cx = g_ekc[tk * 512 + c] + bc0[c];
        float z  = sigf(g_v0h[r * 1024 + 512 + c] + g_ekg[tk * 1024 + 512 + c]);
        float ho = hOld[(size_t)r * 3584 + c];
        hNew[(size_t)r * 3584 + c] = z * ho + (1.0f - z) * tanhf_(a + cx);
      };
      gemm_chunk(A, Kc0 + 32 * 512, 512, ch * 16, 512, red, epi);
    }
    gbar();

    // Ph3: gates1 (N=2048,K=1536) + c1x (N=1024,K=512)
    for (int ch = bid; ch < 192; ch += NBLK) {
      AccH A{hNew, hOld, 0, 512};
      if (ch < 128) {
        auto epi = [&](int r, int c, float a) { g_v1[r * 2048 + c] = a + bg1[c]; };
        gemm_chunk(A, Kg1, 2048, ch * 16, 1536, red, epi);
      } else {
        auto epi = [&](int r, int c, float a) { g_c1x[r * 1024 + c] = a + bc1[c]; };
        gemm_chunk(A, Kc1, 1024, (ch - 128) * 16, 512, red, epi);
      }
    }
    gbar();

    // Ph4: cand1 -> h1'  (N=1024, K=1024)
    for (int ch = bid; ch < 64; ch += NBLK) {
      AccRH A{g_v1, 2048, hOld + 512};
      auto epi = [&](int r, int c, float a) {
        float z  = sigf(g_v1[r * 2048 + 1024 + c]);
        float cx = g_c1x[r * 1024 + c];
        float ho = hOld[(size_t)r * 3584 + 512 + c];
        hNew[(size_t)r * 3584 + 512 + c] = z * ho + (1.0f - z) * tanhf_(a + cx);
      };
      gemm_chunk(A, Kc1 + 512 * 1024, 1024, ch * 16, 1024, red, epi);
    }
    gbar();

    // Ph5: gates2 (N=4096,K=3072) + c2x (N=2048,K=1024)
    for (int ch = bid; ch < 384; ch += NBLK) {
      AccH A{hNew, hOld, 512, 1024};
      if (ch < 256) {
        auto epi = [&](int r, int c, float a) { g_v2[r * 4096 + c] = a + bg2[c]; };
        gemm_chunk(A, Kg2, 4096, ch * 16, 3072, red, epi);
      } else {
        auto epi = [&](int r, int c, float a) { g_c2x[r * 2048 + c] = a + bc2[c]; };
        gemm_chunk(A, Kc2, 2048, (ch - 256) * 16, 1024, red, epi);
      }
    }
    gbar();

    // Ph6: cand2 -> h2'  (N=2048, K=2048)
    for (int ch = bid; ch < 128; ch += NBLK) {
      AccRH A{g_v2, 4096, hOld + 1536};
      auto epi = [&](int r, int c, float a) {
        float z  = sigf(g_v2[r * 4096 + 2048 + c]);
        float cx = g_c2x[r * 2048 + c];
        float ho = hOld[(size_t)r * 3584 + 1536 + c];
        hNew[(size_t)r * 3584 + 1536 + c] = z * ho + (1.0f - z) * tanhf_(a + cx);
      };
      gemm_chunk(A, Kc2 + 1024 * 2048, 2048, ch * 16, 2048, red, epi);
    }
    gbar();

    // Ph7: decode(t) on blocks 0..63  ||  gates0h(t+1) on blocks 64..255
    if (bid < 64) {
      const int b = bid;
      float acc = 0.0f;
      if (tid < 320) {
        const int v = tid >> 3, p = tid & 7;
        for (int i = 0; i < 64; ++i) {
          const int k = p * 4 + i * 32;
          float4 h = *(const float4*)(hNew + (size_t)b * 3584 + 1536 + k);
          acc += h.x * dec_W[k * 40 + v] + h.y * dec_W[(k + 1) * 40 + v] +
                 h.z * dec_W[(k + 2) * 40 + v] + h.w * dec_W[(k + 3) * 40 + v];
        }
        acc += __shfl_xor(acc, 4);
        acc += __shfl_xor(acc, 2);
        acc += __shfl_xor(acc, 1);
        if (p == 0) lg[v] = acc;
      }
      __syncthreads();
      if (tid == 0) {
        int idx = 0; float best = lg[0];
        for (int v = 1; v < 40; ++v) { if (lg[v] > best) { best = lg[v]; idx = v; } }
        const int dn = g_done[b];
        out[b * 50 + t] = dn ? 0.0f : (float)idx;
        float* olg = out + 3200 + (size_t)(b * 50 + t) * 40;
        for (int v = 0; v < 40; ++v) olg[v] = dn ? 0.0f : lg[v];
        if (!dn) { g_tok[b] = idx; if (idx == 0) g_done[b] = 1; }
      }
    } else {
      for (int ch = bid - 64; ch < 64; ch += NBLK - 64) {
        AccH A{hNew, hOld, 0, 512};   // reads h0' (all-new)
        auto epi = [&](int r, int c, float a) { g_v0h[r * 1024 + c] = a + bg0[c]; };
        gemm_chunk(A, Kg0 + 32 * 1024, 1024, ch * 16, 512, red, epi);
      }
    }
    gbar();
  }
}

extern "C" void kernel_launch(void* const* d_in, const int* in_sizes, int n_in,
                              void* d_out, int out_size, void* d_ws, size_t ws_size,
                              hipStream_t stream) {
  (void)in_sizes; (void)n_in; (void)d_ws; (void)ws_size; (void)out_size;
  void* p0  = d_in[0];  void* p1  = d_in[1];  void* p2  = d_in[2];
  void* p3  = d_in[3];  void* p4  = d_in[4];  void* p5  = d_in[5];
  void* p6  = d_in[6];  void* p7  = d_in[7];  void* p8  = d_in[8];
  void* p9  = d_in[9];  void* p10 = d_in[10]; void* p11 = d_in[11];
  void* p12 = d_in[12]; void* p13 = d_in[13]; void* p14 = d_in[14];
  void* p15 = d_in[15]; void* p16 = d_in[16]; void* po  = d_out;
  void* args[] = {&p0, &p1, &p2, &p3, &p4, &p5, &p6, &p7, &p8,
                  &p9, &p10, &p11, &p12, &p13, &p14, &p15, &p16, &po};
  hipLaunchCooperativeKernel((const void*)decoder_kernel, dim3(NBLK), dim3(TPB),
                             args, 0, stream);
}

// Round 6
// 20326.535 us; speedup vs baseline: 5.8239x; 1.4175x over previous
//
#include <hip/hip_runtime.h>
#include <math.h>

#define NBLK 256
#define TPB  512
#define KB   128           // K-tile
#define ATS  65            // A-tile (transposed) row stride, floats
#define WTS  36            // W-tile row stride, floats
// LDS union: stage = AT[KB][ATS] (8320 f) + WT[KB][WTS] (4608 f) = 12928 f
//            red   = 4 * 64 * 33 = 8448 f   (aliased, used after K-loop)
#define LDSF 12928

// ---------------- static device state ----------------
// tree barrier lines (128B apart): grpcnt[16]@g*32, grpgen[16]@512+g*32,
// rootcnt@1024, rootgen@1056, abort@1088. Monotonic; zero-init by module load;
// invariants preserved across graph replays (all counts advance by mult of 16).
#define GC 0
#define GG 512
#define RC 1024
#define RG 1056
#define AB 1088
__device__ unsigned g_sync[1120];
__device__ int g_tok[64];
__device__ int g_done[64];
__device__ __attribute__((aligned(16))) float g_hA[64 * 3584];
__device__ __attribute__((aligned(16))) float g_hB[64 * 3584];
__device__ __attribute__((aligned(16))) float g_v0h[64 * 1024];
__device__ __attribute__((aligned(16))) float g_v1[64 * 2048];
__device__ __attribute__((aligned(16))) float g_c1x[64 * 1024];
__device__ __attribute__((aligned(16))) float g_v2[64 * 4096];
__device__ __attribute__((aligned(16))) float g_c2x[64 * 2048];
__device__ __attribute__((aligned(16))) float g_ekg[40 * 1024];
__device__ __attribute__((aligned(16))) float g_ekc[40 * 512];

__device__ __forceinline__ float sigf(float x) { return 1.0f / (1.0f + __expf(-x)); }
__device__ __forceinline__ float tanhf_(float x) {
  float ax = fabsf(x);
  float e  = __expf(-2.0f * ax);
  float r  = (1.0f - e) / (1.0f + e);
  return copysignf(r, x);
}

// Coherent-point RMW (cross-XCD safe even relaxed; R4/R5 lesson). v=0 = fresh read.
__device__ __forceinline__ unsigned armw(unsigned* p, unsigned v) {
  return __hip_atomic_fetch_add(p, v, __ATOMIC_RELAXED, __HIP_MEMORY_SCOPE_AGENT);
}

// ---------------- A-matrix accessors ----------------
struct AccP {
  const float* p; int lda;
  __device__ __forceinline__ float4 ld(int r, int k) const {
    return *(const float4*)(p + (size_t)r * lda + k);
  }
};
struct AccH {   // hcat: k<cut from pn else po, both at offset `off`
  const float* pn; const float* po; int off; int cut;
  __device__ __forceinline__ float4 ld(int r, int k) const {
    const float* b = (k < cut) ? pn : po;
    return *(const float4*)(b + (size_t)r * 3584 + off + k);
  }
};
struct AccRH0 {
  const float* v; const float* ek; const int* tk; const float* h;
  __device__ __forceinline__ float4 ld(int r, int k) const {
    int t = tk[r];
    float4 a  = *(const float4*)(v + (size_t)r * 1024 + k);
    float4 b  = *(const float4*)(ek + (size_t)t * 1024 + k);
    float4 hh = *(const float4*)(h + (size_t)r * 3584 + k);
    return make_float4(sigf(a.x + b.x) * hh.x, sigf(a.y + b.y) * hh.y,
                       sigf(a.z + b.z) * hh.z, sigf(a.w + b.w) * hh.w);
  }
};
struct AccRH {
  const float* v; int ldv; const float* h;
  __device__ __forceinline__ float4 ld(int r, int k) const {
    float4 a  = *(const float4*)(v + (size_t)r * ldv + k);
    float4 hh = *(const float4*)(h + (size_t)r * 3584 + k);
    return make_float4(sigf(a.x) * hh.x, sigf(a.y) * hh.y,
                       sigf(a.z) * hh.z, sigf(a.w) * hh.w);
  }
};

// ---------------- LDS-staged GEMM chunk: 64 rows x 32 cols x K ----------------
// 8 waves, k interleaved (wave w does k ≡ w mod 8). Per lane: 4 rows x 8 cols.
// Staging: A transposed to AT[k][r] (pad 65), W to WT[k][c] (pad 36).
// Async split: next tile's global loads issued before compute (latency hidden).
#define FMA8(J, AJ) \
  acc[J][0] = fmaf(AJ, wv0.x, acc[J][0]); acc[J][1] = fmaf(AJ, wv0.y, acc[J][1]); \
  acc[J][2] = fmaf(AJ, wv0.z, acc[J][2]); acc[J][3] = fmaf(AJ, wv0.w, acc[J][3]); \
  acc[J][4] = fmaf(AJ, wv1.x, acc[J][4]); acc[J][5] = fmaf(AJ, wv1.y, acc[J][5]); \
  acc[J][6] = fmaf(AJ, wv1.z, acc[J][6]); acc[J][7] = fmaf(AJ, wv1.w, acc[J][7]);

template <class AF, class EF>
__device__ __forceinline__ void gemm32(const AF& A, const float* __restrict__ W,
                                       const int ldw, const int c0, const int K,
                                       float* __restrict__ lds, const EF& epi) {
  float* AT = lds;
  float* WT = lds + KB * ATS;
  const int tid  = threadIdx.x;
  const int w    = tid >> 6;
  const int lane = tid & 63;
  const int rgrp = lane & 15;
  const int cg   = lane >> 4;
  // staging mapping
  const int sr = tid >> 3;            // A row 0..63
  const int sk = (tid & 7) * 16;      // A k-window (16 k)
  const int wr = tid >> 2;            // W row 0..127
  const int wc = (tid & 3) * 8;       // W col window (8)

  float acc[4][8];
#pragma unroll
  for (int j = 0; j < 4; ++j)
#pragma unroll
    for (int e = 0; e < 8; ++e) acc[j][e] = 0.0f;

  float4 aR0, aR1, aR2, aR3, wR0, wR1;
  // prologue: tile 0 global loads
  aR0 = A.ld(sr, sk + 0);  aR1 = A.ld(sr, sk + 4);
  aR2 = A.ld(sr, sk + 8);  aR3 = A.ld(sr, sk + 12);
  {
    const float* wp = W + (size_t)wr * ldw + c0 + wc;
    wR0 = *(const float4*)(wp); wR1 = *(const float4*)(wp + 4);
  }
  const int NT = K / KB;
  for (int t = 0; t < NT; ++t) {
    __syncthreads();                  // LDS free (prev tile computed)
    // write staged regs -> LDS (A transposed)
#pragma unroll
    for (int u = 0; u < 4; ++u) {
      float x = (u == 0) ? aR0.x : (u == 1) ? aR1.x : (u == 2) ? aR2.x : aR3.x;
      float y = (u == 0) ? aR0.y : (u == 1) ? aR1.y : (u == 2) ? aR2.y : aR3.y;
      float z = (u == 0) ? aR0.z : (u == 1) ? aR1.z : (u == 2) ? aR2.z : aR3.z;
      float q = (u == 0) ? aR0.w : (u == 1) ? aR1.w : (u == 2) ? aR2.w : aR3.w;
      AT[(sk + 4 * u + 0) * ATS + sr] = x;
      AT[(sk + 4 * u + 1) * ATS + sr] = y;
      AT[(sk + 4 * u + 2) * ATS + sr] = z;
      AT[(sk + 4 * u + 3) * ATS + sr] = q;
    }
    *(float4*)&WT[wr * WTS + wc]     = wR0;
    *(float4*)&WT[wr * WTS + wc + 4] = wR1;
    // issue next tile loads (latency hides under compute below)
    if (t + 1 < NT) {
      const int kb2 = (t + 1) * KB;
      aR0 = A.ld(sr, kb2 + sk + 0);  aR1 = A.ld(sr, kb2 + sk + 4);
      aR2 = A.ld(sr, kb2 + sk + 8);  aR3 = A.ld(sr, kb2 + sk + 12);
      const float* wp = W + (size_t)(kb2 + wr) * ldw + c0 + wc;
      wR0 = *(const float4*)(wp); wR1 = *(const float4*)(wp + 4);
    }
    __syncthreads();                  // tile staged
#pragma unroll
    for (int i = 0; i < KB / 8; ++i) {
      const int kt = i * 8 + w;
      const float a0 = AT[kt * ATS + rgrp * 4 + 0];
      const float a1 = AT[kt * ATS + rgrp * 4 + 1];
      const float a2 = AT[kt * ATS + rgrp * 4 + 2];
      const float a3 = AT[kt * ATS + rgrp * 4 + 3];
      const float4 wv0 = *(const float4*)&WT[kt * WTS + cg * 8];
      const float4 wv1 = *(const float4*)&WT[kt * WTS + cg * 8 + 4];
      FMA8(0, a0) FMA8(1, a1) FMA8(2, a2) FMA8(3, a3)
    }
  }
  // ---- cross-wave tree reduction (red aliases stage buffers) ----
  float* red = lds;
  const int rb = (rgrp * 4) * 33 + cg * 8;
#define RED_STORE(S) { float* rp = red + (S) * 2112 + rb; \
  _Pragma("unroll") for (int j = 0; j < 4; ++j) _Pragma("unroll") \
    for (int e = 0; e < 8; ++e) rp[j * 33 + e] = acc[j][e]; }
#define RED_ADD(S) { float* rp = red + (S) * 2112 + rb; \
  _Pragma("unroll") for (int j = 0; j < 4; ++j) _Pragma("unroll") \
    for (int e = 0; e < 8; ++e) acc[j][e] += rp[j * 33 + e]; }
  __syncthreads();
  if (w >= 4) RED_STORE(w - 4);
  __syncthreads();
  if (w < 4) RED_ADD(w);
  __syncthreads();
  if (w == 2 || w == 3) RED_STORE(w - 2);
  __syncthreads();
  if (w < 2) RED_ADD(w);
  __syncthreads();
  if (w == 1) RED_STORE(0);
  __syncthreads();
  if (w == 0) {
    RED_ADD(0);
#pragma unroll
    for (int j = 0; j < 4; ++j)
#pragma unroll
      for (int e = 0; e < 8; ++e)
        epi(rgrp * 4 + j, c0 + cg * 8 + e, acc[j][e]);
  }
#undef RED_STORE
#undef RED_ADD
}

// ---------------- the persistent kernel ----------------
__global__ void __launch_bounds__(TPB, 2) decoder_kernel(
    const float* __restrict__ input_vecs, const float* __restrict__ emb,
    const float* __restrict__ dense_W, const float* __restrict__ dense_b,
    const float* __restrict__ dec_W,
    const float* __restrict__ Kg0, const float* __restrict__ bg0,
    const float* __restrict__ Kc0, const float* __restrict__ bc0,
    const float* __restrict__ Kg1, const float* __restrict__ bg1,
    const float* __restrict__ Kc1, const float* __restrict__ bc1,
    const float* __restrict__ Kg2, const float* __restrict__ bg2,
    const float* __restrict__ Kc2, const float* __restrict__ bc2,
    float* __restrict__ out) {
  __shared__ float lds[LDSF];
  __shared__ float lg[40];
  const int bid = blockIdx.x;
  const int tid = threadIdx.x;
  const int grp = bid >> 4;

  // tree-barrier state (tid 0 only); bases read before first arrive => replay-safe
  unsigned epoch = 0, gbase = 0, rbase = 0;
  if (tid == 0) {
    gbase = armw(&g_sync[GG + grp * 32], 0u);
    rbase = armw(&g_sync[RG], 0u);
  }
  auto gbar = [&]() {
    __syncthreads();
    if (tid == 0) {
      __builtin_amdgcn_fence(__ATOMIC_RELEASE, "agent");     // wbl2 once
      ++epoch;
      unsigned a = armw(&g_sync[GC + grp * 32], 1u) + 1u;
      if ((a & 15u) == 0u) {                                  // group closer
        unsigned r = armw(&g_sync[RC], 1u) + 1u;
        if ((r & 15u) == 0u) armw(&g_sync[RG], 1u);           // root publish
        unsigned polls = 0;
        while ((int)(armw(&g_sync[RG], 0u) - rbase) < (int)epoch) {
          __builtin_amdgcn_s_sleep(8);
          if ((++polls & 255u) == 0u) {
            if (polls > (1u << 20)) { armw(&g_sync[AB], 1u); break; }
            if (armw(&g_sync[AB], 0u) != 0u) break;
          }
        }
        armw(&g_sync[GG + grp * 32], 1u);                     // group publish
      } else {
        unsigned polls = 0;
        while ((int)(armw(&g_sync[GG + grp * 32], 0u) - gbase) < (int)epoch) {
          __builtin_amdgcn_s_sleep(8);
          if ((++polls & 255u) == 0u) {
            if (polls > (1u << 20)) { armw(&g_sync[AB], 1u); break; }
            if (armw(&g_sync[AB], 0u) != 0u) break;
          }
        }
      }
    }
    __syncthreads();
    __builtin_amdgcn_fence(__ATOMIC_ACQUIRE, "agent");        // one buffer_inv/wave
  };

  // ---- init: h = input_vecs @ dense_W + b (112 chunks); emb tables; tok ----
  if (bid < 112) {
    AccP A{input_vecs, 512};
    auto epi = [&](int r, int c, float v) { g_hA[(size_t)r * 3584 + c] = v + dense_b[c]; };
    gemm32(A, dense_W, 3584, bid * 32, 512, lds, epi);
  }
  if (bid >= NBLK - 32) {
    int base = (bid - (NBLK - 32)) * 1920;
    for (int o = base + tid; o < base + 1920; o += TPB) {
      if (o < 40960) {
        int r = o >> 10, c = o & 1023;
        float s = 0.0f;
        for (int k = 0; k < 32; ++k) s += emb[r * 32 + k] * Kg0[k * 1024 + c];
        g_ekg[o] = s;
      } else {
        int o2 = o - 40960;
        int r = o2 >> 9, c = o2 & 511;
        float s = 0.0f;
        for (int k = 0; k < 32; ++k) s += emb[r * 32 + k] * Kc0[k * 512 + c];
        g_ekc[o2] = s;
      }
    }
  }
  if (bid == 128 && tid < 64) { g_tok[tid] = 39; g_done[tid] = 0; }
  gbar();

  // ---- t0 gates0h: v0h = bg0 + h0 @ Kg0h (32 chunks) ----
  if (bid < 32) {
    AccH A{g_hA, g_hA, 0, 512};
    auto epi = [&](int r, int c, float v) { g_v0h[r * 1024 + c] = v + bg0[c]; };
    gemm32(A, Kg0 + 32 * 1024, 1024, bid * 32, 512, lds, epi);
  }
  gbar();

  for (int t = 0; t < 50; ++t) {
    const float* hOld = (t & 1) ? g_hB : g_hA;
    float*       hNew = (t & 1) ? g_hA : g_hB;

    // Ph2: cand0 -> h0' (16 chunks, K=512)
    if (bid < 16) {
      AccRH0 A{g_v0h, g_ekg, g_tok, hOld};
      auto epi = [&](int r, int c, float v) {
        int tk = g_tok[r];
        float cx = g_ekc[tk * 512 + c] + bc0[c];
        float z  = sigf(g_v0h[r * 1024 + 512 + c] + g_ekg[tk * 1024 + 512 + c]);
        float ho = hOld[(size_t)r * 3584 + c];
        hNew[(size_t)r * 3584 + c] = z * ho + (1.0f - z) * tanhf_(v + cx);
      };
      gemm32(A, Kc0 + 32 * 512, 512, bid * 32, 512, lds, epi);
    }
    gbar();

    // Ph3: gates1 (64 chunks, K=1536) + c1x (32 chunks, K=512)
    if (bid < 96) {
      AccH A{hNew, hOld, 0, 512};
      if (bid < 64) {
        auto epi = [&](int r, int c, float v) { g_v1[r * 2048 + c] = v + bg1[c]; };
        gemm32(A, Kg1, 2048, bid * 32, 1536, lds, epi);
      } else {
        auto epi = [&](int r, int c, float v) { g_c1x[r * 1024 + c] = v + bc1[c]; };
        gemm32(A, Kc1, 1024, (bid - 64) * 32, 512, lds, epi);
      }
    }
    gbar();

    // Ph4: cand1 -> h1' (32 chunks, K=1024)
    if (bid < 32) {
      AccRH A{g_v1, 2048, hOld + 512};
      auto epi = [&](int r, int c, float v) {
        float z  = sigf(g_v1[r * 2048 + 1024 + c]);
        float cx = g_c1x[r * 1024 + c];
        float ho = hOld[(size_t)r * 3584 + 512 + c];
        hNew[(size_t)r * 3584 + 512 + c] = z * ho + (1.0f - z) * tanhf_(v + cx);
      };
      gemm32(A, Kc1 + 512 * 1024, 1024, bid * 32, 1024, lds, epi);
    }
    gbar();

    // Ph5: gates2 (128 chunks, K=3072) + c2x (64 chunks, K=1024)
    if (bid < 192) {
      AccH A{hNew, hOld, 512, 1024};
      if (bid < 128) {
        auto epi = [&](int r, int c, float v) { g_v2[r * 4096 + c] = v + bg2[c]; };
        gemm32(A, Kg2, 4096, bid * 32, 3072, lds, epi);
      } else {
        auto epi = [&](int r, int c, float v) { g_c2x[r * 2048 + c] = v + bc2[c]; };
        gemm32(A, Kc2, 2048, (bid - 128) * 32, 1024, lds, epi);
      }
    }
    gbar();

    // Ph6: cand2 -> h2' (64 chunks, K=2048)
    if (bid < 64) {
      AccRH A{g_v2, 4096, hOld + 1536};
      auto epi = [&](int r, int c, float v) {
        float z  = sigf(g_v2[r * 4096 + 2048 + c]);
        float cx = g_c2x[r * 2048 + c];
        float ho = hOld[(size_t)r * 3584 + 1536 + c];
        hNew[(size_t)r * 3584 + 1536 + c] = z * ho + (1.0f - z) * tanhf_(v + cx);
      };
      gemm32(A, Kc2 + 1024 * 2048, 2048, bid * 32, 2048, lds, epi);
    }
    gbar();

    // Ph7: decode(t) on blocks 0..63 || gates0h(t+1) on blocks 64..95
    if (bid < 64) {
      const int b = bid;
      float acc = 0.0f;
      if (tid < 320) {
        const int v = tid >> 3, p = tid & 7;
        for (int i = 0; i < 64; ++i) {
          const int k = p * 4 + i * 32;
          float4 h = *(const float4*)(hNew + (size_t)b * 3584 + 1536 + k);
          acc += h.x * dec_W[k * 40 + v] + h.y * dec_W[(k + 1) * 40 + v] +
                 h.z * dec_W[(k + 2) * 40 + v] + h.w * dec_W[(k + 3) * 40 + v];
        }
        acc += __shfl_xor(acc, 4);
        acc += __shfl_xor(acc, 2);
        acc += __shfl_xor(acc, 1);
        if (p == 0) lg[v] = acc;
      }
      __syncthreads();
      if (tid == 0) {
        int idx = 0; float best = lg[0];
        for (int v = 1; v < 40; ++v) { if (lg[v] > best) { best = lg[v]; idx = v; } }
        const int dn = g_done[b];
        out[b * 50 + t] = dn ? 0.0f : (float)idx;
        float* olg = out + 3200 + (size_t)(b * 50 + t) * 40;
        for (int v = 0; v < 40; ++v) olg[v] = dn ? 0.0f : lg[v];
        if (!dn) { g_tok[b] = idx; if (idx == 0) g_done[b] = 1; }
      }
    } else if (bid < 96) {
      AccH A{hNew, hOld, 0, 512};     // reads h0' (all-new)
      auto epi = [&](int r, int c, float v) { g_v0h[r * 1024 + c] = v + bg0[c]; };
      gemm32(A, Kg0 + 32 * 1024, 1024, (bid - 64) * 32, 512, lds, epi);
    }
    gbar();
  }
}

extern "C" void kernel_launch(void* const* d_in, const int* in_sizes, int n_in,
                              void* d_out, int out_size, void* d_ws, size_t ws_size,
                              hipStream_t stream) {
  (void)in_sizes; (void)n_in; (void)d_ws; (void)ws_size; (void)out_size;
  void* p0  = d_in[0];  void* p1  = d_in[1];  void* p2  = d_in[2];
  void* p3  = d_in[3];  void* p4  = d_in[4];  void* p5  = d_in[5];
  void* p6  = d_in[6];  void* p7  = d_in[7];  void* p8  = d_in[8];
  void* p9  = d_in[9];  void* p10 = d_in[10]; void* p11 = d_in[11];
  void* p12 = d_in[12]; void* p13 = d_in[13]; void* p14 = d_in[14];
  void* p15 = d_in[15]; void* p16 = d_in[16]; void* po  = d_out;
  void* args[] = {&p0, &p1, &p2, &p3, &p4, &p5, &p6, &p7, &p8,
                  &p9, &p10, &p11, &p12, &p13, &p14, &p15, &p16, &po};
  hipLaunchCooperativeKernel((const void*)decoder_kernel, dim3(NBLK), dim3(TPB),
                             args, 0, stream);
}

// Round 7
// 19221.956 us; speedup vs baseline: 6.1585x; 1.0575x over previous
//
#include <hip/hip_runtime.h>
#include <math.h>

#define NBLK 256
#define TPB  512
#define KB   128          // K-tile
#define ATS  65           // transposed A-tile row stride (floats)
// LDS: AT = KB*ATS = 8320 f; red = 4*64*33 = 8448 f (aliased after K-loop);
// decode h2row = 2048 f (aliased). LDSF = max = 8448 floats (~33.8 KB).
#define LDSF 8448

// ---------------- static device state ----------------
#define GC 0
#define GG 512
#define RC 1024
#define RG 1056
#define AB 1088
__device__ unsigned g_sync[1120];
__device__ int g_tok[64];
__device__ int g_done[64];
__device__ __attribute__((aligned(16))) float g_hA[64 * 3584];
__device__ __attribute__((aligned(16))) float g_hB[64 * 3584];
__device__ __attribute__((aligned(16))) float g_v0h[64 * 1024];
__device__ __attribute__((aligned(16))) float g_v1a[64 * 2048];
__device__ __attribute__((aligned(16))) float g_v1b[64 * 2048];
__device__ __attribute__((aligned(16))) float g_c1x[64 * 1024];
__device__ __attribute__((aligned(16))) float g_v2a[64 * 4096];
__device__ __attribute__((aligned(16))) float g_v2b[64 * 4096];
__device__ __attribute__((aligned(16))) float g_cnd2a[64 * 2048];
__device__ __attribute__((aligned(16))) float g_cnd2b[64 * 2048];
__device__ __attribute__((aligned(16))) float g_c2x[64 * 2048];
__device__ __attribute__((aligned(16))) float g_ekg[40 * 1024];
__device__ __attribute__((aligned(16))) float g_ekc[40 * 512];

__device__ __forceinline__ float sigf(float x) { return 1.0f / (1.0f + __expf(-x)); }
__device__ __forceinline__ float tanhf_(float x) {
  float ax = fabsf(x);
  float e  = __expf(-2.0f * ax);
  float r  = (1.0f - e) / (1.0f + e);
  return copysignf(r, x);
}

// Coherent-point RMW (cross-XCD safe even relaxed; R4/R5 lesson). v=0 = fresh read.
__device__ __forceinline__ unsigned armw(unsigned* p, unsigned v) {
  return __hip_atomic_fetch_add(p, v, __ATOMIC_RELAXED, __HIP_MEMORY_SCOPE_AGENT);
}

// ---------------- A accessors (float4 over global k) ----------------
struct AccP {   // plain [r][k] row-major, stride lda
  const float* p; int lda;
  __device__ __forceinline__ float4 ld(int r, int k) const {
    return *(const float4*)(p + (size_t)r * lda + k);
  }
};
struct AccH {   // hcat: k<cut -> pn, else po; both rows at hcat offset `off`
  const float* pn; const float* po; int off; int cut;
  __device__ __forceinline__ float4 ld(int r, int k) const {
    const float* b = (k < cut) ? pn : po;
    return *(const float4*)(b + (size_t)r * 3584 + off + k);
  }
};
struct AccRH0 { // layer0 cand A: sigmoid(v0h + ekg[tok]) * h0_old
  const float* v; const float* ek; const int* tk; const float* h;
  __device__ __forceinline__ float4 ld(int r, int k) const {
    int t = tk[r];
    float4 a  = *(const float4*)(v + (size_t)r * 1024 + k);
    float4 b  = *(const float4*)(ek + (size_t)t * 1024 + k);
    float4 hh = *(const float4*)(h + (size_t)r * 3584 + k);
    return make_float4(sigf(a.x + b.x) * hh.x, sigf(a.y + b.y) * hh.y,
                       sigf(a.z + b.z) * hh.z, sigf(a.w + b.w) * hh.w);
  }
};
struct AccR1 {  // layer1 cand A: sigmoid(v1a+v1b) * h1_old
  const float* va; const float* vb; const float* h;   // h pre-offset (+512)
  __device__ __forceinline__ float4 ld(int r, int k) const {
    float4 a  = *(const float4*)(va + (size_t)r * 2048 + k);
    float4 b  = *(const float4*)(vb + (size_t)r * 2048 + k);
    float4 hh = *(const float4*)(h + (size_t)r * 3584 + k);
    return make_float4(sigf(a.x + b.x) * hh.x, sigf(a.y + b.y) * hh.y,
                       sigf(a.z + b.z) * hh.z, sigf(a.w + b.w) * hh.w);
  }
};
struct AccR2 {  // layer2 cand A: sigmoid(v2a+v2b) * h2_old
  const float* va; const float* vb; const float* h;   // h pre-offset (+1536)
  __device__ __forceinline__ float4 ld(int r, int k) const {
    float4 a  = *(const float4*)(va + (size_t)r * 4096 + k);
    float4 b  = *(const float4*)(vb + (size_t)r * 4096 + k);
    float4 hh = *(const float4*)(h + (size_t)r * 3584 + k);
    return make_float4(sigf(a.x + b.x) * hh.x, sigf(a.y + b.y) * hh.y,
                       sigf(a.z + b.z) * hh.z, sigf(a.w + b.w) * hh.w);
  }
};
template <class Inner> struct AccOff {  // k-offset wrapper for split-K
  Inner in; int base;
  __device__ __forceinline__ float4 ld(int r, int k) const { return in.ld(r, base + k); }
};

// ---------------- GEMM chunk: 64 rows x 32 cols x K ----------------
// A staged transposed in LDS (read b128 conflict-free, read-once-per-element).
// W read DIRECTLY from global per wave (broadcast over 16 lanes, L1/L2-served,
// depth-1 prefetch) — LDS round-trip for single-use W removed (R6 lesson).
// 8 waves k-interleaved (wave w: k ≡ w mod 8); lane tile 4 rows x 8 cols.
#define FMA8(J, AJ) \
  acc[J][0] = fmaf(AJ, wv0.x, acc[J][0]); acc[J][1] = fmaf(AJ, wv0.y, acc[J][1]); \
  acc[J][2] = fmaf(AJ, wv0.z, acc[J][2]); acc[J][3] = fmaf(AJ, wv0.w, acc[J][3]); \
  acc[J][4] = fmaf(AJ, wv1.x, acc[J][4]); acc[J][5] = fmaf(AJ, wv1.y, acc[J][5]); \
  acc[J][6] = fmaf(AJ, wv1.z, acc[J][6]); acc[J][7] = fmaf(AJ, wv1.w, acc[J][7]);

template <class AF, class EF>
__device__ __forceinline__ void gemm32(const AF& A, const float* __restrict__ W,
                                       const int ldw, const int c0, const int K,
                                       float* __restrict__ lds, const EF& epi) {
  float* AT = lds;
  const int tid  = threadIdx.x;
  const int w    = tid >> 6;
  const int lane = tid & 63;
  const int rgrp = lane & 15;
  const int cg   = lane >> 4;
  const int sr = tid >> 3;            // A row 0..63
  const int sk = (tid & 7) * 16;      // A k-window (16 k)

  float acc[4][8];
#pragma unroll
  for (int j = 0; j < 4; ++j)
#pragma unroll
    for (int e = 0; e < 8; ++e) acc[j][e] = 0.0f;

  float4 aR0 = A.ld(sr, sk + 0), aR1 = A.ld(sr, sk + 4);
  float4 aR2 = A.ld(sr, sk + 8), aR3 = A.ld(sr, sk + 12);

  const int NT = K / KB;
  const float* wbase = W + (size_t)w * ldw + c0 + cg * 8;

  for (int t = 0; t < NT; ++t) {
    __syncthreads();                  // LDS free (prev tile consumed)
    AT[(sk + 0)  * ATS + sr] = aR0.x;  AT[(sk + 1)  * ATS + sr] = aR0.y;
    AT[(sk + 2)  * ATS + sr] = aR0.z;  AT[(sk + 3)  * ATS + sr] = aR0.w;
    AT[(sk + 4)  * ATS + sr] = aR1.x;  AT[(sk + 5)  * ATS + sr] = aR1.y;
    AT[(sk + 6)  * ATS + sr] = aR1.z;  AT[(sk + 7)  * ATS + sr] = aR1.w;
    AT[(sk + 8)  * ATS + sr] = aR2.x;  AT[(sk + 9)  * ATS + sr] = aR2.y;
    AT[(sk + 10) * ATS + sr] = aR2.z;  AT[(sk + 11) * ATS + sr] = aR2.w;
    AT[(sk + 12) * ATS + sr] = aR3.x;  AT[(sk + 13) * ATS + sr] = aR3.y;
    AT[(sk + 14) * ATS + sr] = aR3.z;  AT[(sk + 15) * ATS + sr] = aR3.w;
    if (t + 1 < NT) {                 // next-tile A prefetch (hides under compute)
      const int kb2 = (t + 1) * KB;
      aR0 = A.ld(sr, kb2 + sk + 0);  aR1 = A.ld(sr, kb2 + sk + 4);
      aR2 = A.ld(sr, kb2 + sk + 8);  aR3 = A.ld(sr, kb2 + sk + 12);
    }
    __syncthreads();                  // tile staged
    const float* wrow = wbase + (size_t)t * KB * ldw;
    float4 wv0 = *(const float4*)wrow;
    float4 wv1 = *(const float4*)(wrow + 4);
#pragma unroll
    for (int i = 0; i < KB / 8; ++i) {
      const int kt = i * 8 + w;
      const float4 av = *(const float4*)&AT[kt * ATS + rgrp * 4];
      float4 nw0 = wv0, nw1 = wv1;
      if (i + 1 < KB / 8) {           // depth-1 W prefetch
        wrow += (size_t)8 * ldw;
        nw0 = *(const float4*)wrow;
        nw1 = *(const float4*)(wrow + 4);
      }
      FMA8(0, av.x) FMA8(1, av.y) FMA8(2, av.z) FMA8(3, av.w)
      wv0 = nw0; wv1 = nw1;
    }
  }
  // ---- cross-wave tree reduction (red aliases AT) ----
  float* red = lds;
  const int rb = (rgrp * 4) * 33 + cg * 8;
#define RED_STORE(S) { float* rp = red + (S) * 2112 + rb; \
  _Pragma("unroll") for (int j = 0; j < 4; ++j) _Pragma("unroll") \
    for (int e = 0; e < 8; ++e) rp[j * 33 + e] = acc[j][e]; }
#define RED_ADD(S) { float* rp = red + (S) * 2112 + rb; \
  _Pragma("unroll") for (int j = 0; j < 4; ++j) _Pragma("unroll") \
    for (int e = 0; e < 8; ++e) acc[j][e] += rp[j * 33 + e]; }
  __syncthreads();
  if (w >= 4) RED_STORE(w - 4);
  __syncthreads();
  if (w < 4) RED_ADD(w);
  __syncthreads();
  if (w == 2 || w == 3) RED_STORE(w - 2);
  __syncthreads();
  if (w < 2) RED_ADD(w);
  __syncthreads();
  if (w == 1) RED_STORE(0);
  __syncthreads();
  if (w == 0) {
    RED_ADD(0);
#pragma unroll
    for (int j = 0; j < 4; ++j)
#pragma unroll
      for (int e = 0; e < 8; ++e)
        epi(rgrp * 4 + j, c0 + cg * 8 + e, acc[j][e]);
  }
#undef RED_STORE
#undef RED_ADD
}

// ---------------- the persistent kernel ----------------
__global__ void __launch_bounds__(TPB, 2) decoder_kernel(
    const float* __restrict__ input_vecs, const float* __restrict__ emb,
    const float* __restrict__ dense_W, const float* __restrict__ dense_b,
    const float* __restrict__ dec_W,
    const float* __restrict__ Kg0, const float* __restrict__ bg0,
    const float* __restrict__ Kc0, const float* __restrict__ bc0,
    const float* __restrict__ Kg1, const float* __restrict__ bg1,
    const float* __restrict__ Kc1, const float* __restrict__ bc1,
    const float* __restrict__ Kg2, const float* __restrict__ bg2,
    const float* __restrict__ Kc2, const float* __restrict__ bc2,
    float* __restrict__ out) {
  __shared__ float lds[LDSF];
  __shared__ float lg[40];
  const int bid = blockIdx.x;
  const int tid = threadIdx.x;
  const int grp = bid >> 4;

  unsigned epoch = 0, gbase = 0, rbase = 0;
  if (tid == 0) {
    gbase = armw(&g_sync[GG + grp * 32], 0u);
    rbase = armw(&g_sync[RG], 0u);
  }
  auto gbar = [&]() {
    __syncthreads();
    if (tid == 0) {
      __builtin_amdgcn_fence(__ATOMIC_RELEASE, "agent");     // wbl2 once
      ++epoch;
      unsigned a = armw(&g_sync[GC + grp * 32], 1u) + 1u;
      if ((a & 15u) == 0u) {
        unsigned r = armw(&g_sync[RC], 1u) + 1u;
        if ((r & 15u) == 0u) armw(&g_sync[RG], 1u);
        unsigned polls = 0;
        while ((int)(armw(&g_sync[RG], 0u) - rbase) < (int)epoch) {
          __builtin_amdgcn_s_sleep(8);
          if ((++polls & 255u) == 0u) {
            if (polls > (1u << 20)) { armw(&g_sync[AB], 1u); break; }
            if (armw(&g_sync[AB], 0u) != 0u) break;
          }
        }
        armw(&g_sync[GG + grp * 32], 1u);
      } else {
        unsigned polls = 0;
        while ((int)(armw(&g_sync[GG + grp * 32], 0u) - gbase) < (int)epoch) {
          __builtin_amdgcn_s_sleep(8);
          if ((++polls & 255u) == 0u) {
            if (polls > (1u << 20)) { armw(&g_sync[AB], 1u); break; }
            if (armw(&g_sync[AB], 0u) != 0u) break;
          }
        }
      }
    }
    __syncthreads();
    __builtin_amdgcn_fence(__ATOMIC_ACQUIRE, "agent");       // one buffer_inv/wave
  };

  // ---- init: h = input_vecs @ dense_W + b (112 chunks); emb tables; tok ----
  if (bid < 112) {
    AccP A{input_vecs, 512};
    auto epi = [&](int r, int c, float v) { g_hA[(size_t)r * 3584 + c] = v + dense_b[c]; };
    gemm32(A, dense_W, 3584, bid * 32, 512, lds, epi);
  }
  if (bid >= NBLK - 32) {
    int base = (bid - (NBLK - 32)) * 1920;
    for (int o = base + tid; o < base + 1920; o += TPB) {
      if (o < 40960) {
        int r = o >> 10, c = o & 1023;
        float s = 0.0f;
        for (int k = 0; k < 32; ++k) s += emb[r * 32 + k] * Kg0[k * 1024 + c];
        g_ekg[o] = s;
      } else {
        int o2 = o - 40960;
        int r = o2 >> 9, c = o2 & 511;
        float s = 0.0f;
        for (int k = 0; k < 32; ++k) s += emb[r * 32 + k] * Kc0[k * 512 + c];
        g_ekc[o2] = s;
      }
    }
  }
  if (bid == 128 && tid < 64) { g_tok[tid] = 39; g_done[tid] = 0; }
  gbar();

  // ---- t0 gates0h: v0h = bg0 + h0 @ Kg0h (32 chunks) ----
  if (bid < 32) {
    AccP A{g_hA, 3584};
    auto epi = [&](int r, int c, float v) { g_v0h[r * 1024 + c] = v + bg0[c]; };
    gemm32(A, Kg0 + 32 * 1024, 1024, bid * 32, 512, lds, epi);
  }
  gbar();

  for (int t = 0; t < 50; ++t) {
    const float* hOld = (t & 1) ? g_hB : g_hA;
    float*       hNew = (t & 1) ? g_hA : g_hB;

    // Ph2: cand0 -> h0' (16 chunks, K=512)
    if (bid < 16) {
      AccRH0 A{g_v0h, g_ekg, g_tok, hOld};
      auto epi = [&](int r, int c, float v) {
        int tk = g_tok[r];
        float cx = g_ekc[tk * 512 + c] + bc0[c];
        float z  = sigf(g_v0h[r * 1024 + 512 + c] + g_ekg[tk * 1024 + 512 + c]);
        float ho = hOld[(size_t)r * 3584 + c];
        hNew[(size_t)r * 3584 + c] = z * ho + (1.0f - z) * tanhf_(v + cx);
      };
      gemm32(A, Kc0 + 32 * 512, 512, bid * 32, 512, lds, epi);
    }
    gbar();

    // Ph3: gates1 split-K x2 (64 chunks x 2, K=768 each) + c1x (32 chunks, K=512)
    if (bid < 128) {
      const int half = bid >> 6, ch = bid & 63;
      AccOff<AccH> A{{hNew, hOld, 0, 512}, half * 768};
      float* dst = half ? g_v1b : g_v1a;
      if (half == 0) {
        auto epi = [&](int r, int c, float v) { dst[r * 2048 + c] = v + bg1[c]; };
        gemm32(A, Kg1, 2048, ch * 32, 768, lds, epi);
      } else {
        auto epi = [&](int r, int c, float v) { dst[r * 2048 + c] = v; };
        gemm32(A, Kg1 + (size_t)768 * 2048, 2048, ch * 32, 768, lds, epi);
      }
    } else if (bid < 160) {
      AccP A{hNew, 3584};
      auto epi = [&](int r, int c, float v) { g_c1x[r * 1024 + c] = v + bc1[c]; };
      gemm32(A, Kc1, 1024, (bid - 128) * 32, 512, lds, epi);
    }
    gbar();

    // Ph4: cand1 -> h1' (32 chunks, K=1024)
    if (bid < 32) {
      AccR1 A{g_v1a, g_v1b, hOld + 512};
      auto epi = [&](int r, int c, float v) {
        float z  = sigf(g_v1a[r * 2048 + 1024 + c] + g_v1b[r * 2048 + 1024 + c]);
        float cx = g_c1x[r * 1024 + c];
        float ho = hOld[(size_t)r * 3584 + 512 + c];
        hNew[(size_t)r * 3584 + 512 + c] = z * ho + (1.0f - z) * tanhf_(v + cx);
      };
      gemm32(A, Kc1 + (size_t)512 * 1024, 1024, bid * 32, 1024, lds, epi);
    }
    gbar();

    // Ph5: gates2 split-K x2 (128 chunks x 2, K=1536 each)
    {
      const int half = bid >> 7, ch = bid & 127;
      AccOff<AccH> A{{hNew, hOld, 512, 1024}, half * 1536};
      if (half == 0) {
        auto epi = [&](int r, int c, float v) { g_v2a[(size_t)r * 4096 + c] = v + bg2[c]; };
        gemm32(A, Kg2, 4096, ch * 32, 1536, lds, epi);
      } else {
        auto epi = [&](int r, int c, float v) { g_v2b[(size_t)r * 4096 + c] = v; };
        gemm32(A, Kg2 + (size_t)1536 * 4096, 4096, ch * 32, 1536, lds, epi);
      }
    }
    gbar();

    // Ph6: cand2 split-K x2, RAW partials (64 chunks x 2, K=1024)
    //      + c2x (64 chunks, K=1024)   [c2x legal here: combine deferred to Ph7]
    if (bid < 128) {
      const int half = bid >> 6, ch = bid & 63;
      AccOff<AccR2> A{{g_v2a, g_v2b, hOld + 1536}, half * 1024};
      float* dst = half ? g_cnd2b : g_cnd2a;
      auto epi = [&](int r, int c, float v) { dst[r * 2048 + c] = v; };
      gemm32(A, Kc2 + (size_t)(1024 + half * 1024) * 2048, 2048, ch * 32, 1024, lds, epi);
    } else if (bid < 192) {
      AccP A{hNew + 512, 3584};
      auto epi = [&](int r, int c, float v) { g_c2x[r * 2048 + c] = v + bc2[c]; };
      gemm32(A, Kc2, 2048, (bid - 128) * 32, 1024, lds, epi);
    }
    gbar();

    // Ph7: decode+combine h2' (blocks 0..63) || gates0h(t+1) (blocks 64..95)
    if (bid < 64) {
      const int b = bid;
      float* h2row = lds;              // 2048 floats
      {
        const int c = tid * 4;
        float4 va = *(const float4*)&g_v2a[(size_t)b * 4096 + 2048 + c];
        float4 vb = *(const float4*)&g_v2b[(size_t)b * 4096 + 2048 + c];
        float4 ca = *(const float4*)&g_cnd2a[b * 2048 + c];
        float4 cb = *(const float4*)&g_cnd2b[b * 2048 + c];
        float4 cx = *(const float4*)&g_c2x[b * 2048 + c];
        float4 ho = *(const float4*)&hOld[(size_t)b * 3584 + 1536 + c];
        float4 r;
#define GRU2(comp) { float z = sigf(va.comp + vb.comp); \
        r.comp = z * ho.comp + (1.0f - z) * tanhf_(ca.comp + cb.comp + cx.comp); }
        GRU2(x) GRU2(y) GRU2(z) GRU2(w)
#undef GRU2
        *(float4*)&hNew[(size_t)b * 3584 + 1536 + c] = r;
        *(float4*)&h2row[c] = r;
      }
      __syncthreads();
      float acc = 0.0f;
      if (tid < 320) {
        const int v = tid >> 3, p = tid & 7;
        for (int i = 0; i < 64; ++i) {
          const int k = p * 4 + i * 32;
          float4 h = *(const float4*)&h2row[k];
          acc += h.x * dec_W[k * 40 + v] + h.y * dec_W[(k + 1) * 40 + v] +
                 h.z * dec_W[(k + 2) * 40 + v] + h.w * dec_W[(k + 3) * 40 + v];
        }
        acc += __shfl_xor(acc, 4);
        acc += __shfl_xor(acc, 2);
        acc += __shfl_xor(acc, 1);
        if (p == 0) lg[v] = acc;
      }
      __syncthreads();
      if (tid == 0) {
        int idx = 0; float best = lg[0];
        for (int v = 1; v < 40; ++v) { if (lg[v] > best) { best = lg[v]; idx = v; } }
        const int dn = g_done[b];
        out[b * 50 + t] = dn ? 0.0f : (float)idx;
        float* olg = out + 3200 + (size_t)(b * 50 + t) * 40;
        for (int v = 0; v < 40; ++v) olg[v] = dn ? 0.0f : lg[v];
        if (!dn) { g_tok[b] = idx; if (idx == 0) g_done[b] = 1; }
      }
    } else if (bid < 96) {
      AccP A{hNew, 3584};             // reads h0' (all-new)
      auto epi = [&](int r, int c, float v) { g_v0h[r * 1024 + c] = v + bg0[c]; };
      gemm32(A, Kg0 + 32 * 1024, 1024, (bid - 64) * 32, 512, lds, epi);
    }
    gbar();
  }
}

extern "C" void kernel_launch(void* const* d_in, const int* in_sizes, int n_in,
                              void* d_out, int out_size, void* d_ws, size_t ws_size,
                              hipStream_t stream) {
  (void)in_sizes; (void)n_in; (void)d_ws; (void)ws_size; (void)out_size;
  void* p0  = d_in[0];  void* p1  = d_in[1];  void* p2  = d_in[2];
  void* p3  = d_in[3];  void* p4  = d_in[4];  void* p5  = d_in[5];
  void* p6  = d_in[6];  void* p7  = d_in[7];  void* p8  = d_in[8];
  void* p9  = d_in[9];  void* p10 = d_in[10]; void* p11 = d_in[11];
  void* p12 = d_in[12]; void* p13 = d_in[13]; void* p14 = d_in[14];
  void* p15 = d_in[15]; void* p16 = d_in[16]; void* po  = d_out;
  void* args[] = {&p0, &p1, &p2, &p3, &p4, &p5, &p6, &p7, &p8,
                  &p9, &p10, &p11, &p12, &p13, &p14, &p15, &p16, &po};
  hipLaunchCooperativeKernel((const void*)decoder_kernel, dim3(NBLK), dim3(TPB),
                             args, 0, stream);
}